// Round 3
// baseline (134.104 us; speedup 1.0000x reference)
//
#include <hip/hip_runtime.h>
#include <stdint.h>

#define IN_DIM 4096

typedef float f32x4 __attribute__((ext_vector_type(4)));

__global__ __launch_bounds__(256) void snn_step_kernel(
    const int*   __restrict__ x,    // (IN,1) int32 binary spikes
    const f32x4* __restrict__ W,    // (OUT,IN) f32, 4 elems per vec
    const f32x4* __restrict__ T,    // trace
    const f32x4* __restrict__ D,    // delay (small non-negative ints as f32)
    const float* __restrict__ dtp,
    const float* __restrict__ taup,
    const float* __restrict__ alp,
    f32x4* __restrict__ O0,         // weight * spike_out
    f32x4* __restrict__ O1,         // trace_new
    int iters,                      // full strided iterations per thread
    int nvec)                       // OUT*IN/4 (for tail guard)
{
    const float k  = (*dtp) / (*taup);  // dt/tau
    const float al = *alp;

    const int tid    = blockIdx.x * blockDim.x + threadIdx.x;
    const int stride = gridDim.x * blockDim.x;

    #pragma unroll 4
    for (int it = 0; it < iters; ++it) {
        const int v = tid + it * stride;
        const int col = (v * 4) & (IN_DIM - 1);   // row-major, IN divisible by 4
        const int4  xv = *(const int4*)(x + col);
        const f32x4 wv = W[v];
        const f32x4 tv = T[v];
        const f32x4 dv = D[v];

        f32x4 o, n;
        {
            const float xf0 = (float)xv.x, xf1 = (float)xv.y,
                        xf2 = (float)xv.z, xf3 = (float)xv.w;
            // trace_new = trace + k*(-trace + alpha*x)   (reference op order)
            n.x = tv.x + k * (al * xf0 - tv.x);
            n.y = tv.y + k * (al * xf1 - tv.y);
            n.z = tv.z + k * (al * xf2 - tv.z);
            n.w = tv.w + k * (al * xf3 - tv.w);
            // spike = ((d>0 ? d-1 : d) == 1); d is an exact small int
            o.x = ((dv.x > 0.0f ? dv.x - 1.0f : dv.x) == 1.0f) ? wv.x : 0.0f;
            o.y = ((dv.y > 0.0f ? dv.y - 1.0f : dv.y) == 1.0f) ? wv.y : 0.0f;
            o.z = ((dv.z > 0.0f ? dv.z - 1.0f : dv.z) == 1.0f) ? wv.z : 0.0f;
            o.w = ((dv.w > 0.0f ? dv.w - 1.0f : dv.w) == 1.0f) ? wv.w : 0.0f;
        }
        // Non-temporal stores: outputs are write-once, never re-read this pass.
        // Keep them from evicting the W/T/D read set out of the 256 MiB LLC.
        __builtin_nontemporal_store(o, O0 + v);
        __builtin_nontemporal_store(n, O1 + v);
    }

    // Tail (not taken for the bench shape: nvec = iters * stride exactly)
    int v = tid + iters * stride;
    if (v < nvec) {
        const int col = (v * 4) & (IN_DIM - 1);
        const int4  xv = *(const int4*)(x + col);
        const f32x4 wv = W[v];
        const f32x4 tv = T[v];
        const f32x4 dv = D[v];
        f32x4 o, n;
        n.x = tv.x + k * (al * (float)xv.x - tv.x);
        n.y = tv.y + k * (al * (float)xv.y - tv.y);
        n.z = tv.z + k * (al * (float)xv.z - tv.z);
        n.w = tv.w + k * (al * (float)xv.w - tv.w);
        o.x = ((dv.x > 0.0f ? dv.x - 1.0f : dv.x) == 1.0f) ? wv.x : 0.0f;
        o.y = ((dv.y > 0.0f ? dv.y - 1.0f : dv.y) == 1.0f) ? wv.y : 0.0f;
        o.z = ((dv.z > 0.0f ? dv.z - 1.0f : dv.z) == 1.0f) ? wv.z : 0.0f;
        o.w = ((dv.w > 0.0f ? dv.w - 1.0f : dv.w) == 1.0f) ? wv.w : 0.0f;
        __builtin_nontemporal_store(o, O0 + v);
        __builtin_nontemporal_store(n, O1 + v);
    }
}

extern "C" void kernel_launch(void* const* d_in, const int* in_sizes, int n_in,
                              void* d_out, int out_size, void* d_ws, size_t ws_size,
                              hipStream_t stream) {
    // setup_inputs order: x, weight, trace, delay, delay_init(UNUSED), dt, tau_t, alpha_t
    const int*   x  = (const int*)d_in[0];
    const f32x4* W  = (const f32x4*)d_in[1];
    const f32x4* T  = (const f32x4*)d_in[2];
    const f32x4* D  = (const f32x4*)d_in[3];
    // d_in[4] = delay_init: dead in the reference (delay_new is deleted) — never read.
    const float* dtp  = (const float*)d_in[5];
    const float* taup = (const float*)d_in[6];
    const float* alp  = (const float*)d_in[7];

    const int n_elems = in_sizes[1];        // OUT*IN = 33,554,432
    const int nvec    = n_elems / 4;        // 4 f32 per vec

    f32x4* O0 = (f32x4*)d_out;                       // output 0, flat f32
    f32x4* O1 = (f32x4*)((float*)d_out + n_elems);   // output 1 follows

    const int block  = 256;
    const int grid   = 2048;                // 524288 threads
    const int stride = grid * block;
    const int iters  = nvec / stride;       // 16 for the bench shape
    snn_step_kernel<<<grid, block, 0, stream>>>(x, W, T, D, dtp, taup, alp,
                                                O0, O1, iters, nvec);
}

// Round 4
// 133.744 us; speedup vs baseline: 1.0027x; 1.0027x over previous
//
#include <hip/hip_runtime.h>
#include <stdint.h>

#define IN_DIM 4096

typedef float f32x4 __attribute__((ext_vector_type(4)));

__global__ __launch_bounds__(256) void snn_step_kernel(
    const int*   __restrict__ x,    // (IN,1) int32 binary spikes
    const f32x4* __restrict__ W,    // (OUT,IN) f32, 4 elems per vec
    const f32x4* __restrict__ T,    // trace
    const f32x4* __restrict__ D,    // delay (small non-negative ints as f32)
    const float* __restrict__ dtp,
    const float* __restrict__ taup,
    const float* __restrict__ alp,
    f32x4* __restrict__ O0,         // weight * spike_out
    f32x4* __restrict__ O1,         // trace_new
    int iters,                      // full strided iterations per thread
    int nvec)                       // OUT*IN/4 (tail guard)
{
    const float k  = (*dtp) / (*taup);  // dt/tau
    const float al = *alp;

    const int tid    = blockIdx.x * blockDim.x + threadIdx.x;
    const int stride = gridDim.x * blockDim.x;

    // stride*4 is a multiple of IN_DIM for our launch config, so this thread's
    // column block -- and therefore its x values -- are loop-invariant. One
    // x read per thread for the whole kernel.
    const int col = (tid * 4) & (IN_DIM - 1);
    const int4 xv = *(const int4*)(x + col);
    const float ax0 = al * (float)xv.x;
    const float ax1 = al * (float)xv.y;
    const float ax2 = al * (float)xv.z;
    const float ax3 = al * (float)xv.w;

    #pragma unroll 4
    for (int it = 0; it < iters; ++it) {
        const int v = tid + it * stride;
        const f32x4 wv = W[v];
        const f32x4 tv = T[v];
        const f32x4 dv = D[v];

        f32x4 o, n;
        // trace_new = trace + k*(-trace + alpha*x)   (reference op order)
        n.x = tv.x + k * (ax0 - tv.x);
        n.y = tv.y + k * (ax1 - tv.y);
        n.z = tv.z + k * (ax2 - tv.z);
        n.w = tv.w + k * (ax3 - tv.w);
        // spike = ((d>0 ? d-1 : d) == 1); d is an exact small int  ->  d == 2
        o.x = ((dv.x > 0.0f ? dv.x - 1.0f : dv.x) == 1.0f) ? wv.x : 0.0f;
        o.y = ((dv.y > 0.0f ? dv.y - 1.0f : dv.y) == 1.0f) ? wv.y : 0.0f;
        o.z = ((dv.z > 0.0f ? dv.z - 1.0f : dv.z) == 1.0f) ? wv.z : 0.0f;
        o.w = ((dv.w > 0.0f ? dv.w - 1.0f : dv.w) == 1.0f) ? wv.w : 0.0f;

        O0[v] = o;
        O1[v] = n;
    }

    // Tail (not taken for the bench shape: nvec == iters * stride)
    const int v = tid + iters * stride;
    if (v < nvec) {
        const int c2 = (v * 4) & (IN_DIM - 1);
        const int4 xt = *(const int4*)(x + c2);
        const f32x4 wv = W[v];
        const f32x4 tv = T[v];
        const f32x4 dv = D[v];
        f32x4 o, n;
        n.x = tv.x + k * (al * (float)xt.x - tv.x);
        n.y = tv.y + k * (al * (float)xt.y - tv.y);
        n.z = tv.z + k * (al * (float)xt.z - tv.z);
        n.w = tv.w + k * (al * (float)xt.w - tv.w);
        o.x = ((dv.x > 0.0f ? dv.x - 1.0f : dv.x) == 1.0f) ? wv.x : 0.0f;
        o.y = ((dv.y > 0.0f ? dv.y - 1.0f : dv.y) == 1.0f) ? wv.y : 0.0f;
        o.z = ((dv.z > 0.0f ? dv.z - 1.0f : dv.z) == 1.0f) ? wv.z : 0.0f;
        o.w = ((dv.w > 0.0f ? dv.w - 1.0f : dv.w) == 1.0f) ? wv.w : 0.0f;
        O0[v] = o;
        O1[v] = n;
    }
}

extern "C" void kernel_launch(void* const* d_in, const int* in_sizes, int n_in,
                              void* d_out, int out_size, void* d_ws, size_t ws_size,
                              hipStream_t stream) {
    // setup_inputs order: x, weight, trace, delay, delay_init(UNUSED), dt, tau_t, alpha_t
    const int*   x  = (const int*)d_in[0];
    const f32x4* W  = (const f32x4*)d_in[1];
    const f32x4* T  = (const f32x4*)d_in[2];
    const f32x4* D  = (const f32x4*)d_in[3];
    // d_in[4] = delay_init: dead in the reference (delay_new is deleted) — never read.
    const float* dtp  = (const float*)d_in[5];
    const float* taup = (const float*)d_in[6];
    const float* alp  = (const float*)d_in[7];

    const int n_elems = in_sizes[1];        // OUT*IN = 33,554,432
    const int nvec    = n_elems / 4;        // 4 f32 per vec

    f32x4* O0 = (f32x4*)d_out;                       // output 0, flat f32
    f32x4* O1 = (f32x4*)((float*)d_out + n_elems);   // output 1 follows

    // 4x block oversubscription (32 blocks/CU queued, 8 resident): the
    // dispatcher backfills finished blocks, hiding per-block rate variance.
    // stride*4 floats = 8192*256*4*4 is a multiple of IN_DIM=4096 -> x hoist valid.
    const int block  = 256;
    const int grid   = 8192;
    const int stride = grid * block;        // in vec units
    const int iters  = nvec / stride;       // 4 for the bench shape
    snn_step_kernel<<<grid, block, 0, stream>>>(x, W, T, D, dtp, taup, alp,
                                                O0, O1, iters, nvec);
}